// Round 7
// baseline (229.577 us; speedup 1.0000x reference)
//
#include <hip/hip_runtime.h>
#include <hip/hip_fp16.h>

constexpr int N_NODES = 50000;
constexpr int N_EDGES = 400000;
constexpr int F = 128;

typedef _Float16 f16x8 __attribute__((ext_vector_type(8)));
typedef _Float16 f16x4 __attribute__((ext_vector_type(4)));
typedef _Float16 f16x2 __attribute__((ext_vector_type(2)));
typedef float    f32x4 __attribute__((ext_vector_type(4)));

union v8v2 { f16x8 v8; f16x2 v2[4]; };

// XOR swizzle: flips half-index bits 3..5 by row&7 -> conflict-free frag reads.
__device__ __forceinline__ int swz(int row, int colh) {
    return (row * F + colh) ^ ((row & 7) << 3);
}

// ---------------- Kernel 1: weight fusion (tiny) ----------------
// Wall slots (f16 [128][128], natural [o][d]):
//   0: W_lin[0], 1: Wf[0]=W_att[0]@W_lin[0], 2: W_lin[1], 3: Wf[1]
// ball slots (f32 [128]): 0: b[0], 1: W_att[0]@b[0], 2: b[1], 3: W_att[1]@b[1]
__global__ __launch_bounds__(256) void gat_fuse(
    const float* __restrict__ W_lin, const float* __restrict__ b_lin,
    const float* __restrict__ W_att,
    _Float16* __restrict__ Wall, float* __restrict__ ball)
{
    __shared__ float wl[128][8];
    const int h  = blockIdx.x >> 4;
    const int cb = blockIdx.x & 15;
    const int t  = threadIdx.x;
    const float* WL = W_lin + h * F * F;
    const float* WA = W_att + h * F * F;

    {   int p = t >> 1, d0 = (t & 1) * 4;
        float4 v = *(const float4*)(WL + p * F + cb * 8 + d0);
        wl[p][d0+0]=v.x; wl[p][d0+1]=v.y; wl[p][d0+2]=v.z; wl[p][d0+3]=v.w;
    }
    __syncthreads();

    {   int o = t >> 1, j2 = (t & 1) * 4;
        float a0=0, a1=0, a2=0, a3=0;
        const float* war = WA + o * F;
        #pragma unroll 4
        for (int p = 0; p < F; ++p) {
            float wa = war[p];
            a0 += wa * wl[p][j2+0]; a1 += wa * wl[p][j2+1];
            a2 += wa * wl[p][j2+2]; a3 += wa * wl[p][j2+3];
        }
        f16x4 hv; hv[0]=(_Float16)a0; hv[1]=(_Float16)a1;
        hv[2]=(_Float16)a2; hv[3]=(_Float16)a3;
        *(f16x4*)(Wall + (2*h+1) * F * F + o * F + cb * 8 + j2) = hv;
    }

    {   int idx = cb * 1024 + t * 4;
        float4 v = *(const float4*)(WL + idx);
        f16x4 hv; hv[0]=(_Float16)v.x; hv[1]=(_Float16)v.y;
        hv[2]=(_Float16)v.z; hv[3]=(_Float16)v.w;
        *(f16x4*)(Wall + 2*h * F * F + idx) = hv;
    }

    if (cb == 0 && t < F) {
        ball[2*h * F + t] = b_lin[h * F + t];
        float acc = 0;
        const float* war = WA + t * F;
        for (int p = 0; p < F; ++p) acc += war[p] * b_lin[h * F + p];
        ball[(2*h+1) * F + t] = acc;
    }
}

// ---------------- Edge sort: counting sort by row>>7 (391 buckets) --------
__global__ __launch_bounds__(256) void gat_hist(
    const int* __restrict__ ei, unsigned* __restrict__ cnt)
{
    __shared__ unsigned h[512];
    int t = threadIdx.x;
    h[t] = 0; h[t + 256] = 0;
    __syncthreads();
    int base = blockIdx.x * 1024;
    #pragma unroll
    for (int i = 0; i < 4; ++i) {
        int e = base + t + i * 256;
        if (e < N_EDGES) atomicAdd(&h[ei[e] >> 7], 1u);
    }
    __syncthreads();
    if (h[t])       atomicAdd(&cnt[t], h[t]);
    if (h[t + 256]) atomicAdd(&cnt[t + 256], h[t + 256]);
}

__global__ __launch_bounds__(512) void gat_prefix(
    const unsigned* __restrict__ cnt, unsigned* __restrict__ offs)
{
    __shared__ unsigned s[512];
    int t = threadIdx.x;
    s[t] = cnt[t];
    __syncthreads();
    #pragma unroll
    for (int d = 1; d < 512; d <<= 1) {
        unsigned v = (t >= d) ? s[t - d] : 0u;
        __syncthreads();
        s[t] += v;
        __syncthreads();
    }
    offs[t] = s[t] - cnt[t];          // exclusive prefix
}

__global__ __launch_bounds__(256) void gat_scatter(
    const int* __restrict__ ei, unsigned* __restrict__ offs,
    uint2* __restrict__ sorted)
{
    int e = blockIdx.x * 256 + threadIdx.x;
    if (e >= N_EDGES) return;
    int r = ei[e], c = ei[N_EDGES + e];
    unsigned pos = atomicAdd(&offs[r >> 7], 1u);
    sorted[pos] = make_uint2((unsigned)r | ((unsigned)c << 16), (unsigned)e);
}

// ---------------- Kernel 2: GEMM with prefetch + coalesced epilogue -------
// 128 nodes/block, 32/wave; 4 weight slots serial with next-slot reg prefetch;
// outputs staged per-wave in LDS -> full-line 64B-segment global stores.
__global__ __launch_bounds__(256) void gat_gemm(
    const float* __restrict__ x,        // [N][128]
    const _Float16* __restrict__ Wall,  // [4][128][128]
    const float* __restrict__ ball,     // [4][128]
    _Float16* __restrict__ HX,          // [N][2][128]
    _Float16* __restrict__ A2)          // [N][2][128]
{
    __shared__ _Float16 wbuf[F * F];       // 32 KB
    __shared__ _Float16 stag[4][16 * F];   // 16 KB (per-wave 4 KB)

    const int t    = threadIdx.x;
    const int wave = t >> 6;
    const int lane = t & 63;
    const int r16  = lane & 15;
    const int kgrp = lane >> 4;
    const int node_base = blockIdx.x * 128 + wave * 32;

    // x frags: 2 node groups of 16, f32 -> f16, persistent across slots
    f16x8 xf[2][4];
    #pragma unroll
    for (int g = 0; g < 2; ++g) {
        int xrow = node_base + g * 16 + r16;
        if (xrow >= N_NODES) xrow = N_NODES - 1;
        const float* xp = x + (size_t)xrow * F + kgrp * 8;
        #pragma unroll
        for (int kk = 0; kk < 4; ++kk) {
            float4 v0 = *(const float4*)(xp + kk * 32);
            float4 v1 = *(const float4*)(xp + kk * 32 + 4);
            f16x8 hv;
            hv[0]=(_Float16)v0.x; hv[1]=(_Float16)v0.y;
            hv[2]=(_Float16)v0.z; hv[3]=(_Float16)v0.w;
            hv[4]=(_Float16)v1.x; hv[5]=(_Float16)v1.y;
            hv[6]=(_Float16)v1.z; hv[7]=(_Float16)v1.w;
            xf[g][kk] = hv;
        }
    }

    // prologue: stage slot 0
    f16x8 pre[8];
    #pragma unroll
    for (int i = 0; i < 8; ++i)
        pre[i] = *(const f16x8*)(Wall + (size_t)(i * 256 + t) * 8);
    #pragma unroll
    for (int i = 0; i < 8; ++i) {
        int idx8 = i * 256 + t;
        *(f16x8*)(wbuf + swz(idx8 >> 4, (idx8 & 15) * 8)) = pre[i];
    }
    __syncthreads();

    #pragma unroll
    for (int slot = 0; slot < 4; ++slot) {
        // T14: issue next slot's global loads before compute
        if (slot < 3) {
            const _Float16* Wn = Wall + (slot + 1) * F * F;
            #pragma unroll
            for (int i = 0; i < 8; ++i)
                pre[i] = *(const f16x8*)(Wn + (size_t)(i * 256 + t) * 8);
        }

        _Float16* dstbase = ((slot & 1) ? A2 : HX) + (slot >> 1) * F;

        #pragma unroll
        for (int g = 0; g < 2; ++g) {
            #pragma unroll
            for (int c = 0; c < 8; ++c) {
                f16x8 aw[4];
                #pragma unroll
                for (int kk = 0; kk < 4; ++kk)
                    aw[kk] = *(const f16x8*)(wbuf + swz(c * 16 + r16, kk * 32 + kgrp * 8));
                f32x4 acc = {0.f, 0.f, 0.f, 0.f};
                #pragma unroll
                for (int kk = 0; kk < 4; ++kk)
                    acc = __builtin_amdgcn_mfma_f32_16x16x32_f16(aw[kk], xf[g][kk], acc, 0, 0, 0);
                float4 bv = *(const float4*)(ball + slot * F + c * 16 + kgrp * 4);
                f16x4 hv;
                hv[0] = (_Float16)(acc[0] + bv.x);
                hv[1] = (_Float16)(acc[1] + bv.y);
                hv[2] = (_Float16)(acc[2] + bv.z);
                hv[3] = (_Float16)(acc[3] + bv.w);
                *(f16x4*)(&stag[wave][swz(r16, c * 16 + kgrp * 4)]) = hv;
            }
            // readback: full-line coalesced stores (16 nodes x 64B per instr)
            int nd = lane >> 2;
            int node = node_base + g * 16 + nd;
            #pragma unroll
            for (int i = 0; i < 4; ++i) {
                int f0 = (lane & 3) * 8 + i * 32;
                f16x8 v = *(const f16x8*)(&stag[wave][swz(nd, f0)]);
                if (node < N_NODES)
                    *(f16x8*)(dstbase + (size_t)node * 256 + f0) = v;
            }
        }
        __syncthreads();                 // all waves done reading wbuf
        if (slot < 3) {
            #pragma unroll
            for (int i = 0; i < 8; ++i) {
                int idx8 = i * 256 + t;
                *(f16x8*)(wbuf + swz(idx8 >> 4, (idx8 & 15) * 8)) = pre[i];
            }
            __syncthreads();
        }
    }
}

// ---------------- Kernel 3: edge scores on sorted list --------------------
// 8 edges/wave, 8 lanes/edge, 64B/lane/side. Bijective XCD-chunked swizzle
// so each XCD walks a contiguous (row-sorted) edge range.
__global__ __launch_bounds__(256) void gat_edge(
    const uint2* __restrict__ sorted,    // packed {r|c<<16, e}
    const _Float16* __restrict__ HX,
    const _Float16* __restrict__ A2,
    float* __restrict__ out)
{
    const int nwg = gridDim.x;
    int bid = blockIdx.x;
    int xcd = bid & 7, loc = bid >> 3;
    int q = nwg >> 3, rr = nwg & 7;
    int wg = (xcd < rr ? xcd * (q + 1) : rr * (q + 1) + (xcd - rr) * q) + loc;

    int lane = threadIdx.x & 63;
    int idx  = wg * 32 + (threadIdx.x >> 6) * 8 + (lane >> 3);
    int hl   = lane & 7;
    if (idx >= N_EDGES) return;

    uint2 rc = sorted[idx];
    int r = rc.x & 0xFFFF;
    int c = rc.x >> 16;

    const _Float16* hp = HX + (size_t)r * 256 + hl * 32;
    const _Float16* ap = A2 + (size_t)c * 256 + hl * 32;
    v8v2 a[4], b[4];
    #pragma unroll
    for (int i = 0; i < 4; ++i) a[i].v8 = *(const f16x8*)(hp + i * 8);
    #pragma unroll
    for (int i = 0; i < 4; ++i) b[i].v8 = *(const f16x8*)(ap + i * 8);

    float p = 0.f;
    #pragma unroll
    for (int i = 0; i < 4; ++i)
        #pragma unroll
        for (int j = 0; j < 4; ++j)
            p = __builtin_amdgcn_fdot2(a[i].v2[j], b[i].v2[j], p, false);

    #pragma unroll
    for (int m = 1; m <= 4; m <<= 1) p += __shfl_xor(p, m);

    if (hl == 0) out[rc.y] = 1.f / (1.f + __expf(-0.5f * p));
}

extern "C" void kernel_launch(void* const* d_in, const int* in_sizes, int n_in,
                              void* d_out, int out_size, void* d_ws, size_t ws_size,
                              hipStream_t stream) {
    const float* x     = (const float*)d_in[0];
    const int*   ei    = (const int*)d_in[1];
    const float* W_lin = (const float*)d_in[2];
    const float* b_lin = (const float*)d_in[3];
    const float* W_att = (const float*)d_in[4];
    float* out = (float*)d_out;

    // ws layout: Wall | ball | HX | A2 | cnt | offs | sorted
    _Float16* Wall = (_Float16*)d_ws;                    // 256 KB
    float*    ball = (float*)(Wall + 4 * F * F);         // 2 KB
    _Float16* HX   = (_Float16*)(ball + 4 * F);          // 25.6 MB
    _Float16* A2   = HX + (size_t)N_NODES * 256;         // 25.6 MB
    unsigned* cnt  = (unsigned*)(A2 + (size_t)N_NODES * 256);  // 2 KB
    unsigned* offs = cnt + 512;                          // 2 KB
    uint2*    sorted = (uint2*)(offs + 512);             // 3.2 MB

    hipMemsetAsync(cnt, 0, 512 * sizeof(unsigned), stream);
    gat_hist<<<(N_EDGES + 1023) / 1024, 256, 0, stream>>>(ei, cnt);
    gat_prefix<<<1, 512, 0, stream>>>(cnt, offs);
    gat_scatter<<<(N_EDGES + 255) / 256, 256, 0, stream>>>(ei, offs, sorted);

    gat_fuse<<<32, 256, 0, stream>>>(W_lin, b_lin, W_att, Wall, ball);
    gat_gemm<<<(N_NODES + 127) / 128, 256, 0, stream>>>(x, Wall, ball, HX, A2);

    gat_edge<<<N_EDGES / 32, 256, 0, stream>>>(sorted, HX, A2, out);
}

// Round 8
// 92.867 us; speedup vs baseline: 2.4721x; 2.4721x over previous
//
#include <hip/hip_runtime.h>
#include <hip/hip_fp16.h>

constexpr int N_NODES = 50000;
constexpr int N_EDGES = 400000;
constexpr int F = 128;

constexpr int NBUK = 512;                       // row>>7 buckets (391 used)
constexpr int EPB  = 4096;                      // edges per hist/scatter block
constexpr int NBLK = (N_EDGES + EPB - 1) / EPB; // 98

typedef _Float16 f16x8 __attribute__((ext_vector_type(8)));
typedef _Float16 f16x4 __attribute__((ext_vector_type(4)));
typedef _Float16 f16x2 __attribute__((ext_vector_type(2)));
typedef float    f32x4 __attribute__((ext_vector_type(4)));

union v8v2 { f16x8 v8; f16x2 v2[4]; };

// XOR swizzle: flips half-index bits 3..5 by row&7 -> conflict-free frag reads.
__device__ __forceinline__ int swz(int row, int colh) {
    return (row * F + colh) ^ ((row & 7) << 3);
}

// ---------------- Kernel 1: weight fusion (tiny) ----------------
// Wall slots (f16 [128][128], natural [o][d]):
//   0: W_lin[0], 1: Wf[0]=W_att[0]@W_lin[0], 2: W_lin[1], 3: Wf[1]
// ball slots (f32 [128]): 0: b[0], 1: W_att[0]@b[0], 2: b[1], 3: W_att[1]@b[1]
__global__ __launch_bounds__(256) void gat_fuse(
    const float* __restrict__ W_lin, const float* __restrict__ b_lin,
    const float* __restrict__ W_att,
    _Float16* __restrict__ Wall, float* __restrict__ ball)
{
    __shared__ float wl[128][8];
    const int h  = blockIdx.x >> 4;
    const int cb = blockIdx.x & 15;
    const int t  = threadIdx.x;
    const float* WL = W_lin + h * F * F;
    const float* WA = W_att + h * F * F;

    {   int p = t >> 1, d0 = (t & 1) * 4;
        float4 v = *(const float4*)(WL + p * F + cb * 8 + d0);
        wl[p][d0+0]=v.x; wl[p][d0+1]=v.y; wl[p][d0+2]=v.z; wl[p][d0+3]=v.w;
    }
    __syncthreads();

    {   int o = t >> 1, j2 = (t & 1) * 4;
        float a0=0, a1=0, a2=0, a3=0;
        const float* war = WA + o * F;
        #pragma unroll 4
        for (int p = 0; p < F; ++p) {
            float wa = war[p];
            a0 += wa * wl[p][j2+0]; a1 += wa * wl[p][j2+1];
            a2 += wa * wl[p][j2+2]; a3 += wa * wl[p][j2+3];
        }
        f16x4 hv; hv[0]=(_Float16)a0; hv[1]=(_Float16)a1;
        hv[2]=(_Float16)a2; hv[3]=(_Float16)a3;
        *(f16x4*)(Wall + (2*h+1) * F * F + o * F + cb * 8 + j2) = hv;
    }

    {   int idx = cb * 1024 + t * 4;
        float4 v = *(const float4*)(WL + idx);
        f16x4 hv; hv[0]=(_Float16)v.x; hv[1]=(_Float16)v.y;
        hv[2]=(_Float16)v.z; hv[3]=(_Float16)v.w;
        *(f16x4*)(Wall + 2*h * F * F + idx) = hv;
    }

    if (cb == 0 && t < F) {
        ball[2*h * F + t] = b_lin[h * F + t];
        float acc = 0;
        const float* war = WA + t * F;
        for (int p = 0; p < F; ++p) acc += war[p] * b_lin[h * F + p];
        ball[(2*h+1) * F + t] = acc;
    }
}

// ---------------- Deterministic counting sort by row>>7 -------------------
// K1: per-block LDS histogram -> bcnt[block][bucket]  (no global atomics)
__global__ __launch_bounds__(256) void gat_hist(
    const int* __restrict__ ei, unsigned* __restrict__ bcnt)
{
    __shared__ unsigned h[NBUK];
    const int t = threadIdx.x, b = blockIdx.x;
    #pragma unroll
    for (int i = 0; i < NBUK / 256; ++i) h[t + i * 256] = 0;
    __syncthreads();
    const int base = b * EPB;
    #pragma unroll
    for (int i = 0; i < EPB / 256; ++i) {
        int e = base + i * 256 + t;
        if (e < N_EDGES) atomicAdd(&h[(unsigned)ei[e] >> 7], 1u);
    }
    __syncthreads();
    #pragma unroll
    for (int i = 0; i < NBUK / 256; ++i)
        bcnt[b * NBUK + t + i * 256] = h[t + i * 256];
}

// K2: one 512-thread block. bucket totals (coalesced) -> LDS exclusive scan
// across buckets -> per-(block,bucket) absolute bases bof[block][bucket].
__global__ __launch_bounds__(NBUK) void gat_scan(
    const unsigned* __restrict__ bcnt, unsigned* __restrict__ bof)
{
    __shared__ unsigned s[NBUK];
    const int B = threadIdx.x;                  // bucket id
    unsigned tot = 0;
    for (int b = 0; b < NBLK; ++b) tot += bcnt[b * NBUK + B];
    s[B] = tot;
    __syncthreads();
    #pragma unroll
    for (int d = 1; d < NBUK; d <<= 1) {
        unsigned u = (B >= d) ? s[B - d] : 0u;
        __syncthreads();
        s[B] += u;
        __syncthreads();
    }
    unsigned run = s[B] - tot;                  // exclusive bucket base
    for (int b = 0; b < NBLK; ++b) {
        bof[b * NBUK + B] = run;
        run += bcnt[b * NBUK + B];
    }
}

// K3: scatter with LDS-atomic ranks only.
__global__ __launch_bounds__(256) void gat_scatter(
    const int* __restrict__ ei, const unsigned* __restrict__ bof,
    uint2* __restrict__ sorted)
{
    __shared__ unsigned base[NBUK];
    const int t = threadIdx.x, b = blockIdx.x;
    #pragma unroll
    for (int i = 0; i < NBUK / 256; ++i)
        base[t + i * 256] = bof[b * NBUK + t + i * 256];
    __syncthreads();
    const int bs = b * EPB;
    #pragma unroll
    for (int i = 0; i < EPB / 256; ++i) {
        int e = bs + i * 256 + t;
        if (e < N_EDGES) {
            unsigned r = (unsigned)ei[e], c = (unsigned)ei[N_EDGES + e];
            unsigned pos = atomicAdd(&base[r >> 7], 1u);
            sorted[pos] = make_uint2(r | (c << 16), (unsigned)e);
        }
    }
}

// ---------------- Kernel 2: GEMM with prefetch + coalesced epilogue -------
__global__ __launch_bounds__(256) void gat_gemm(
    const float* __restrict__ x,        // [N][128]
    const _Float16* __restrict__ Wall,  // [4][128][128]
    const float* __restrict__ ball,     // [4][128]
    _Float16* __restrict__ HX,          // [N][2][128]
    _Float16* __restrict__ A2)          // [N][2][128]
{
    __shared__ _Float16 wbuf[F * F];       // 32 KB
    __shared__ _Float16 stag[4][16 * F];   // 16 KB (per-wave 4 KB)

    const int t    = threadIdx.x;
    const int wave = t >> 6;
    const int lane = t & 63;
    const int r16  = lane & 15;
    const int kgrp = lane >> 4;
    const int node_base = blockIdx.x * 128 + wave * 32;

    f16x8 xf[2][4];
    #pragma unroll
    for (int g = 0; g < 2; ++g) {
        int xrow = node_base + g * 16 + r16;
        if (xrow >= N_NODES) xrow = N_NODES - 1;
        const float* xp = x + (size_t)xrow * F + kgrp * 8;
        #pragma unroll
        for (int kk = 0; kk < 4; ++kk) {
            float4 v0 = *(const float4*)(xp + kk * 32);
            float4 v1 = *(const float4*)(xp + kk * 32 + 4);
            f16x8 hv;
            hv[0]=(_Float16)v0.x; hv[1]=(_Float16)v0.y;
            hv[2]=(_Float16)v0.z; hv[3]=(_Float16)v0.w;
            hv[4]=(_Float16)v1.x; hv[5]=(_Float16)v1.y;
            hv[6]=(_Float16)v1.z; hv[7]=(_Float16)v1.w;
            xf[g][kk] = hv;
        }
    }

    f16x8 pre[8];
    #pragma unroll
    for (int i = 0; i < 8; ++i)
        pre[i] = *(const f16x8*)(Wall + (size_t)(i * 256 + t) * 8);
    #pragma unroll
    for (int i = 0; i < 8; ++i) {
        int idx8 = i * 256 + t;
        *(f16x8*)(wbuf + swz(idx8 >> 4, (idx8 & 15) * 8)) = pre[i];
    }
    __syncthreads();

    #pragma unroll
    for (int slot = 0; slot < 4; ++slot) {
        if (slot < 3) {
            const _Float16* Wn = Wall + (slot + 1) * F * F;
            #pragma unroll
            for (int i = 0; i < 8; ++i)
                pre[i] = *(const f16x8*)(Wn + (size_t)(i * 256 + t) * 8);
        }

        _Float16* dstbase = ((slot & 1) ? A2 : HX) + (slot >> 1) * F;

        #pragma unroll
        for (int g = 0; g < 2; ++g) {
            #pragma unroll
            for (int c = 0; c < 8; ++c) {
                f16x8 aw[4];
                #pragma unroll
                for (int kk = 0; kk < 4; ++kk)
                    aw[kk] = *(const f16x8*)(wbuf + swz(c * 16 + r16, kk * 32 + kgrp * 8));
                f32x4 acc = {0.f, 0.f, 0.f, 0.f};
                #pragma unroll
                for (int kk = 0; kk < 4; ++kk)
                    acc = __builtin_amdgcn_mfma_f32_16x16x32_f16(aw[kk], xf[g][kk], acc, 0, 0, 0);
                float4 bv = *(const float4*)(ball + slot * F + c * 16 + kgrp * 4);
                f16x4 hv;
                hv[0] = (_Float16)(acc[0] + bv.x);
                hv[1] = (_Float16)(acc[1] + bv.y);
                hv[2] = (_Float16)(acc[2] + bv.z);
                hv[3] = (_Float16)(acc[3] + bv.w);
                *(f16x4*)(&stag[wave][swz(r16, c * 16 + kgrp * 4)]) = hv;
            }
            int nd = lane >> 2;
            int node = node_base + g * 16 + nd;
            #pragma unroll
            for (int i = 0; i < 4; ++i) {
                int f0 = (lane & 3) * 8 + i * 32;
                f16x8 v = *(const f16x8*)(&stag[wave][swz(nd, f0)]);
                if (node < N_NODES)
                    *(f16x8*)(dstbase + (size_t)node * 256 + f0) = v;
            }
        }
        __syncthreads();
        if (slot < 3) {
            #pragma unroll
            for (int i = 0; i < 8; ++i) {
                int idx8 = i * 256 + t;
                *(f16x8*)(wbuf + swz(idx8 >> 4, (idx8 & 15) * 8)) = pre[i];
            }
            __syncthreads();
        }
    }
}

// ---------------- Kernel 3: edge scores on sorted list --------------------
// 8 edges/wave, 8 lanes/edge, 64B/lane/side; XCD-chunked bijective swizzle
// so each XCD walks a contiguous (row-sorted) edge range.
__global__ __launch_bounds__(256) void gat_edge(
    const uint2* __restrict__ sorted,    // packed {r|c<<16, e}
    const _Float16* __restrict__ HX,
    const _Float16* __restrict__ A2,
    float* __restrict__ out)
{
    const int nwg = gridDim.x;
    int bid = blockIdx.x;
    int xcd = bid & 7, loc = bid >> 3;
    int q = nwg >> 3, rr = nwg & 7;
    int wg = (xcd < rr ? xcd * (q + 1) : rr * (q + 1) + (xcd - rr) * q) + loc;

    int lane = threadIdx.x & 63;
    int idx  = wg * 32 + (threadIdx.x >> 6) * 8 + (lane >> 3);
    int hl   = lane & 7;
    if (idx >= N_EDGES) return;

    uint2 rc = sorted[idx];
    int r = rc.x & 0xFFFF;
    int c = rc.x >> 16;

    const _Float16* hp = HX + (size_t)r * 256 + hl * 32;
    const _Float16* ap = A2 + (size_t)c * 256 + hl * 32;
    v8v2 a[4], b[4];
    #pragma unroll
    for (int i = 0; i < 4; ++i) a[i].v8 = *(const f16x8*)(hp + i * 8);
    #pragma unroll
    for (int i = 0; i < 4; ++i) b[i].v8 = *(const f16x8*)(ap + i * 8);

    float p = 0.f;
    #pragma unroll
    for (int i = 0; i < 4; ++i)
        #pragma unroll
        for (int j = 0; j < 4; ++j)
            p = __builtin_amdgcn_fdot2(a[i].v2[j], b[i].v2[j], p, false);

    #pragma unroll
    for (int m = 1; m <= 4; m <<= 1) p += __shfl_xor(p, m);

    if (hl == 0) out[rc.y] = 1.f / (1.f + __expf(-0.5f * p));
}

extern "C" void kernel_launch(void* const* d_in, const int* in_sizes, int n_in,
                              void* d_out, int out_size, void* d_ws, size_t ws_size,
                              hipStream_t stream) {
    const float* x     = (const float*)d_in[0];
    const int*   ei    = (const int*)d_in[1];
    const float* W_lin = (const float*)d_in[2];
    const float* b_lin = (const float*)d_in[3];
    const float* W_att = (const float*)d_in[4];
    float* out = (float*)d_out;

    // ws layout: Wall | ball | HX | A2 | bcnt | bof | sorted  (~55 MB)
    _Float16* Wall = (_Float16*)d_ws;                          // 128 KB
    float*    ball = (float*)(Wall + 4 * F * F);               // 2 KB
    _Float16* HX   = (_Float16*)(ball + 4 * F);                // 25.6 MB
    _Float16* A2   = HX + (size_t)N_NODES * 256;               // 25.6 MB
    unsigned* bcnt = (unsigned*)(A2 + (size_t)N_NODES * 256);  // 200 KB
    unsigned* bof  = bcnt + NBLK * NBUK;                       // 200 KB
    uint2*    sorted = (uint2*)(bof + NBLK * NBUK);            // 3.2 MB

    gat_hist<<<NBLK, 256, 0, stream>>>(ei, bcnt);
    gat_scan<<<1, NBUK, 0, stream>>>(bcnt, bof);
    gat_scatter<<<NBLK, 256, 0, stream>>>(ei, bof, sorted);

    gat_fuse<<<32, 256, 0, stream>>>(W_lin, b_lin, W_att, Wall, ball);
    gat_gemm<<<(N_NODES + 127) / 128, 256, 0, stream>>>(x, Wall, ball, HX, A2);

    gat_edge<<<N_EDGES / 32, 256, 0, stream>>>(sorted, HX, A2, out);
}